// Round 5
// baseline (1140.494 us; speedup 1.0000x reference)
//
#include <hip/hip_runtime.h>

// MyRNN: B=128, T=80, E=100, V=10000, U=512
// 8 clusters x 32 member-blocks. Cluster c owns batch rows [16c,16c+16).
// Member m owns output cols [16m,16m+16) of rk0/rk1/k1 (stationary in LDS,
// hi/lo bf16 split).
// R1: acquire/release -> buffer_inv/wbl2 L2 thrash (24us/round). Relaxed only.
// R2/R3: poll-scheme-independent 13us/round -> gather was serialized; batching
//        loads into regs (R4) gave 2.3x.
// R5: flag protocol (drain->post->poll) cost ~3 RTs/exchange on top of data.
//     Now FLAGLESS: each packed h value carries a 1-bit step-parity tag in the
//     lo-word LSB. Consumers batch-load and retry stale slots. ABA-safe with
//     1 bit because inter-round __syncthreads drains vmcnt(0) (HIP visibility
//     semantics), so a slot can only hold one of two ADJACENT step writes,
//     which differ in parity. Poison 0xAA has LSB 0; all writes at step t use
//     parity (t&1)^1, so first writes (t=0 -> 1) differ from poison.

typedef __attribute__((ext_vector_type(8))) short short8;
typedef __attribute__((ext_vector_type(4))) float f32x4;
typedef unsigned long long ull;

#define MFMA16(a,b,c) __builtin_amdgcn_mfma_f32_16x16x32_bf16(a,b,c,0,0,0)
#define LOAD_RLX(p)    __hip_atomic_load((p), __ATOMIC_RELAXED, __HIP_MEMORY_SCOPE_AGENT)
#define STORE_RLX(p,v) __hip_atomic_store((p), (v), __ATOMIC_RELAXED, __HIP_MEMORY_SCOPE_AGENT)

__device__ __forceinline__ short f2bf(float v){
  unsigned u = __float_as_uint(v);
  u = (u + 0x7fffu + ((u >> 16) & 1u)) >> 16;   // RNE to bf16
  return (short)u;
}
__device__ __forceinline__ float bf2f(short s){
  return __uint_as_float(((unsigned)(unsigned short)s) << 16);
}
__device__ __forceinline__ float fast_tanh(float x){
  x = fminf(15.f, fmaxf(-15.f, x));
  float e = __expf(2.f * x);
  return (e - 1.f) * __builtin_amdgcn_rcpf(e + 1.f);
}

__launch_bounds__(128, 1)
__global__ void rnn_kernel(const int* __restrict__ tokens,
                           const float* __restrict__ emb,
                           const float* __restrict__ k0,
                           const float* __restrict__ rk0,
                           const float* __restrict__ b0,
                           const float* __restrict__ k1,
                           const float* __restrict__ rk1,
                           const float* __restrict__ b1,
                           const float* __restrict__ wd,
                           const float* __restrict__ bd,
                           float* __restrict__ out,
                           char* __restrict__ ws)
{
  constexpr int T = 80, E = 100, U = 512;
  const int tid  = threadIdx.x;
  const int cl   = blockIdx.x & 7;    // cluster (XCD-aligned heuristic only)
  const int mem  = blockIdx.x >> 3;   // member 0..31
  const int w    = tid >> 6;          // wave id (0/1)
  const int lane = tid & 63;
  const int m    = lane & 15;         // row (A) / col (B,C)
  const int q    = lane >> 4;         // quad 0..3

  __shared__ __align__(16) short sW[6][16][520];   // rk0 hi/lo, rk1 hi/lo, k1 hi/lo : [col][k]
  __shared__ __align__(16) short sH[2][16][520];   // h / h0 staging hi,lo : [row][k]
  __shared__ __align__(16) short sE[2][16][136];   // emb rows hi,lo (K padded to 128 w/ zeros)
  __shared__ __align__(16) short sK0[2][16][136];  // k0 slice hi,lo : [col][k] (padded)
  __shared__ int   sTok[16][80];
  __shared__ float sB0[16], sB1[16];
  __shared__ float sRed[16][8];

  unsigned* hPk  = (unsigned*)(ws + 16*1024);      // h1 packed (hi<<16 | lo&~1 | par), [128][512]
  unsigned* h0Pk = hPk + 128*U;                    // h0 packed

  // ---------------- prologue: stationary weights -> LDS ----------------
  const float* mats[3] = { rk0, rk1, k1 };
  for (int mi = 0; mi < 3; ++mi){
    const float* G = mats[mi];
    for (int i = tid; i < 16*U; i += 128){
      int k = i >> 4, c = i & 15;
      float v  = G[k*U + mem*16 + c];
      short hi = f2bf(v);
      short lo = f2bf(v - bf2f(hi));
      sW[2*mi+0][c][k] = hi;
      sW[2*mi+1][c][k] = lo;
    }
  }
  for (int i = tid; i < 2*16*136; i += 128){ ((short*)sE)[i] = 0; ((short*)sK0)[i] = 0; }
  __syncthreads();
  for (int i = tid; i < 16*E; i += 128){
    int e = i >> 4, c = i & 15;
    float v  = k0[e*U + mem*16 + c];
    short hi = f2bf(v);
    short lo = f2bf(v - bf2f(hi));
    sK0[0][c][e] = hi; sK0[1][c][e] = lo;
  }
  for (int i = tid; i < 16*T; i += 128){
    int r = i / T, t = i - r*T;
    sTok[r][t] = tokens[(cl*16 + r)*T + t];
  }
  if (tid < 16){ sB0[tid] = b0[mem*16 + tid]; sB1[tid] = b1[mem*16 + tid]; }
  __syncthreads();

  // Tagged gather: batch 32 8B far-loads, retry stale slots until parity
  // matches, unpack into sH. One pass when producers already landed.
  auto gather_tagged = [&](const unsigned* srcPk, unsigned par){
    const ull* s = (const ull*)(srcPk + cl*16*U);
    ull r[32];
    #pragma unroll
    for (int j = 0; j < 32; ++j) r[j] = LOAD_RLX(&s[j*128 + tid]);
    while (true){
      unsigned stale = 0u;
      #pragma unroll
      for (int j = 0; j < 32; ++j){
        unsigned lo32 = (unsigned)r[j], hi32 = (unsigned)(r[j] >> 32);
        if ((((lo32 ^ par) | (hi32 ^ par)) & 1u)) stale |= 1u << j;
      }
      if (!stale) break;
      #pragma unroll
      for (int j = 0; j < 32; ++j)
        if (stale & (1u << j)) r[j] = LOAD_RLX(&s[j*128 + tid]);
    }
    #pragma unroll
    for (int j = 0; j < 32; ++j){
      int i = j*128 + tid, row = i >> 8, c = (i & 255) * 2;
      unsigned p0 = (unsigned)r[j], p1 = (unsigned)(r[j] >> 32);
      *(unsigned*)&sH[0][row][c] = (p0 >> 16)     | (p1 & 0xffff0000u);
      *(unsigned*)&sH[1][row][c] = (p0 & 0xffffu) | (p1 << 16);
    }
  };

  const f32x4 zero4 = {0.f, 0.f, 0.f, 0.f};

  // ---------------- recurrence ----------------
  for (int t = 0; t < T; ++t){
    const unsigned wpar = (t & 1u) ^ 1u;         // parity for ALL writes at step t

    if (t > 0){
      // round-A gather of h (hPk, written at t-1 with parity t&1),
      // with emb staging overlapped behind the in-flight far loads
      const ull* s = (const ull*)(hPk + cl*16*U);
      ull r[32];
      #pragma unroll
      for (int j = 0; j < 32; ++j) r[j] = LOAD_RLX(&s[j*128 + tid]);

      float ev[13];
      #pragma unroll
      for (int p = 0; p < 13; ++p){
        int i = tid + p*128;
        ev[p] = (i < 16*E) ? emb[sTok[i/E][t]*E + (i % E)] : 0.f;
      }

      const unsigned par = t & 1u;
      while (true){
        unsigned stale = 0u;
        #pragma unroll
        for (int j = 0; j < 32; ++j){
          unsigned lo32 = (unsigned)r[j], hi32 = (unsigned)(r[j] >> 32);
          if ((((lo32 ^ par) | (hi32 ^ par)) & 1u)) stale |= 1u << j;
        }
        if (!stale) break;
        #pragma unroll
        for (int j = 0; j < 32; ++j)
          if (stale & (1u << j)) r[j] = LOAD_RLX(&s[j*128 + tid]);
      }
      #pragma unroll
      for (int j = 0; j < 32; ++j){
        int i = j*128 + tid, row = i >> 8, c = (i & 255) * 2;
        unsigned p0 = (unsigned)r[j], p1 = (unsigned)(r[j] >> 32);
        *(unsigned*)&sH[0][row][c] = (p0 >> 16)     | (p1 & 0xffff0000u);
        *(unsigned*)&sH[1][row][c] = (p0 & 0xffffu) | (p1 << 16);
      }
      #pragma unroll
      for (int p = 0; p < 13; ++p){
        int i = tid + p*128;
        if (i < 16*E){
          int row = i / E, e = i % E;
          short hi = f2bf(ev[p]);
          short lo = f2bf(ev[p] - bf2f(hi));
          sE[0][row][e] = hi; sE[1][row][e] = lo;
        }
      }
    } else {
      for (int i = tid; i < 16*E; i += 128){
        int r2 = i / E, e = i - r2*E;
        float v  = emb[sTok[r2][t]*E + e];
        short hi = f2bf(v);
        short lo = f2bf(v - bf2f(hi));
        sE[0][r2][e] = hi; sE[1][r2][e] = lo;
      }
    }
    __syncthreads();

    // ---- round A: h0 = tanh(x@k0 + h@rk0 + b0) (wave0); wave1: h@rk1 partial
    f32x4 z1a = zero4, z1b = zero4, z1c = zero4, z1d = zero4;
    if (w == 0){
      f32x4 za = zero4, zb = zero4, zc = zero4, zd = zero4;
      #pragma unroll
      for (int kk = 0; kk < 4; ++kk){
        short8 ah = *(const short8*)&sE[0][m][kk*32 + q*8];
        short8 al = *(const short8*)&sE[1][m][kk*32 + q*8];
        short8 bh = *(const short8*)&sK0[0][m][kk*32 + q*8];
        short8 bl = *(const short8*)&sK0[1][m][kk*32 + q*8];
        za = MFMA16(ah, bh, za); zb = MFMA16(al, bh, zb);
        zc = MFMA16(ah, bl, zc); zd = MFMA16(al, bl, zd);
      }
      if (t > 0){
        #pragma unroll
        for (int kk = 0; kk < 16; ++kk){
          short8 ah = *(const short8*)&sH[0][m][kk*32 + q*8];
          short8 al = *(const short8*)&sH[1][m][kk*32 + q*8];
          short8 bh = *(const short8*)&sW[0][m][kk*32 + q*8];
          short8 bl = *(const short8*)&sW[1][m][kk*32 + q*8];
          za = MFMA16(ah, bh, za); zb = MFMA16(al, bh, zb);
          zc = MFMA16(ah, bl, zc); zd = MFMA16(al, bl, zd);
        }
      }
      f32x4 z = za; z += zb; z += zc; z += zd;
      #pragma unroll
      for (int r = 0; r < 4; ++r){
        float h0v = fast_tanh(z[r] + sB0[m]);
        short hi = f2bf(h0v);
        short lo = f2bf(h0v - bf2f(hi));
        int gr = cl*16 + q*4 + r, gc = mem*16 + m;
        unsigned pk = ((unsigned)(unsigned short)hi << 16)
                    | ((unsigned)(unsigned short)lo & 0xFFFEu) | wpar;
        STORE_RLX(&h0Pk[gr*U + gc], pk);
      }
    } else {
      if (t > 0){
        #pragma unroll
        for (int kk = 0; kk < 16; ++kk){
          short8 ah = *(const short8*)&sH[0][m][kk*32 + q*8];
          short8 al = *(const short8*)&sH[1][m][kk*32 + q*8];
          short8 bh = *(const short8*)&sW[2][m][kk*32 + q*8];
          short8 bl = *(const short8*)&sW[3][m][kk*32 + q*8];
          z1a = MFMA16(ah, bh, z1a); z1b = MFMA16(al, bh, z1b);
          z1c = MFMA16(ah, bl, z1c); z1d = MFMA16(al, bl, z1d);
        }
      }
    }
    __syncthreads();   // drains vmcnt(0): h0 stores at coherent point (ABA guard) + sH reuse

    // ---- round B: h1 = tanh(h0@k1 + h@rk1 + b1)
    gather_tagged(h0Pk, wpar);
    __syncthreads();
    if (w == 1){
      f32x4 za = zero4, zb = zero4, zc = zero4, zd = zero4;
      #pragma unroll
      for (int kk = 0; kk < 16; ++kk){
        short8 ah = *(const short8*)&sH[0][m][kk*32 + q*8];
        short8 al = *(const short8*)&sH[1][m][kk*32 + q*8];
        short8 bh = *(const short8*)&sW[4][m][kk*32 + q*8];
        short8 bl = *(const short8*)&sW[5][m][kk*32 + q*8];
        za = MFMA16(ah, bh, za); zb = MFMA16(al, bh, zb);
        zc = MFMA16(ah, bl, zc); zd = MFMA16(al, bl, zd);
      }
      f32x4 z = za; z += zb; z += zc; z += zd;
      z += z1a; z += z1b; z += z1c; z += z1d;
      #pragma unroll
      for (int r = 0; r < 4; ++r){
        float h1v = fast_tanh(z[r] + sB1[m]);
        short hi = f2bf(h1v);
        short lo = f2bf(h1v - bf2f(hi));
        int gr = cl*16 + q*4 + r, gc = mem*16 + m;
        unsigned pk = ((unsigned)(unsigned short)hi << 16)
                    | ((unsigned)(unsigned short)lo & 0xFFFEu) | wpar;
        STORE_RLX(&hPk[gr*U + gc], pk);
      }
    }
    __syncthreads();   // drains vmcnt(0): h1 stores at coherent point (ABA guard) + sH reuse
  }

  // ---------------- epilogue: logits = h@wd + bd ; sigmoid ----------------
  if (mem == 0){
    gather_tagged(hPk, 0u);   // t=79 writes carry parity (79&1)^1 = 0
    __syncthreads();
    {
      int row = tid >> 3, seg = tid & 7;
      float acc = 0.f;
      for (int u = seg*64; u < seg*64 + 64; ++u){
        float hv = bf2f(sH[0][row][u]) + bf2f(sH[1][row][u]);
        acc += hv * wd[u];
      }
      sRed[row][seg] = acc;
    }
    __syncthreads();
    if (tid < 16){
      float s = bd[0];
      #pragma unroll
      for (int j = 0; j < 8; ++j) s += sRed[tid][j];
      out[cl*16 + tid] = 1.f / (1.f + __expf(-s));
    }
  }
}

extern "C" void kernel_launch(void* const* d_in, const int* in_sizes, int n_in,
                              void* d_out, int out_size, void* d_ws, size_t ws_size,
                              hipStream_t stream) {
  const int*   tokens = (const int*)  d_in[0];
  const float* emb    = (const float*)d_in[1];
  const float* k0     = (const float*)d_in[2];
  const float* rk0    = (const float*)d_in[3];
  const float* b0     = (const float*)d_in[4];
  const float* k1     = (const float*)d_in[5];
  const float* rk1    = (const float*)d_in[6];
  const float* b1     = (const float*)d_in[7];
  const float* wd     = (const float*)d_in[8];
  const float* bd     = (const float*)d_in[9];

  // No counters/flags: sync is parity-tagged data; 0xAA poison has LSB 0,
  // all step-0 writes carry parity 1. No memset needed.
  hipLaunchKernelGGL(rnn_kernel, dim3(256), dim3(128), 0, stream,
                     tokens, emb, k0, rk0, b0, k1, rk1, b1, wd, bd,
                     (float*)d_out, (char*)d_ws);
}